// Round 1
// baseline (2495.598 us; speedup 1.0000x reference)
//
#include <hip/hip_runtime.h>

// VQ-VAE codebook assignment, fp32-grid-faithful argmin.
// z:   [16, 256, 32, 32] fp32   (M = 16*32*32 = 16384 rows, K = 256)
// emb: [8192, 256] fp32         (N = 8192 codes)
// out: [quantized 4194304][st 4194304][indices-as-float 16384]

#define KDIM 256
#define NCODES 8192
#define MTOTAL 16384
#define MT 64          // rows per block
#define NT 64          // codes per LDS tile
#define LP 65          // padded LDS row stride (conflict-free)
#define ST_OFF 4194304
#define IDX_OFF 8388608

__global__ __launch_bounds__(256, 1) void vq_argmin_kernel(
    const float* __restrict__ z, const float* __restrict__ emb,
    float* __restrict__ out)
{
    __shared__ float z_s[KDIM][LP];   // [k][r]  transposed z tile
    __shared__ float e_s[KDIM][LP];   // [k][nn] transposed emb tile
    __shared__ float z2_s[MT];
    __shared__ float red_d[MT][16];
    __shared__ int   red_n[MT][16];
    __shared__ int   idx_s[MT];

    const int tid  = threadIdx.x;
    const int m0   = blockIdx.x * MT;
    const int nimg = m0 >> 10;        // image index (1024 hw per image; MT=64 divides 1024)
    const int hw0  = m0 & 1023;

    // ---- stage z tile transposed: z_s[k][r] = z[nimg, k, hw0+r]
    {
        const int l = tid & 63;       // r
        const int w = tid >> 6;       // wave id 0..3 -> k range
        const float* zb = z + (size_t)nimg * (KDIM * 1024) + hw0 + l;
        #pragma unroll 4
        for (int i = 0; i < 64; ++i) {
            const int k = (w << 6) + i;
            z_s[k][l] = zb[(size_t)k * 1024];   // coalesced 64-float segments
        }
    }
    __syncthreads();

    // ---- per-row ||z||^2 (fp64 accumulate, rounded to fp32; +-ulp offset is
    //      an exact grid translation -> argmin-invariant)
    if (tid < MT) {
        double s = 0.0;
        for (int k = 0; k < KDIM; ++k) { const double v = (double)z_s[k][tid]; s = fma(v, v, s); }
        z2_s[tid] = (float)s;
    }

    const int g = tid >> 4;   // row group: rows 4g..4g+3
    const int h = tid & 15;   // col group: cols 4h..4h+3 within tile

    float bestd[4] = {3.4e38f, 3.4e38f, 3.4e38f, 3.4e38f};
    int   bestn[4] = {0, 0, 0, 0};

    for (int nt = 0; nt < NCODES / NT; ++nt) {
        __syncthreads();   // previous tile's readers done before overwrite
        {   // stage emb tile transposed: e_s[k][nn] = emb[n0+nn, k]
            const float* eb = emb + (size_t)(nt * NT) * KDIM + tid;
            #pragma unroll 4
            for (int nn = 0; nn < NT; ++nn) {
                e_s[tid][nn] = eb[(size_t)nn * KDIM];  // coalesced reads, conflict-free writes
            }
        }
        __syncthreads();

        double acc[4][4];
        #pragma unroll
        for (int i = 0; i < 4; ++i)
            #pragma unroll
            for (int j = 0; j < 4; ++j) acc[i][j] = 0.0;

        for (int k = 0; k < KDIM; ++k) {
            double zd[4], ed[4];
            #pragma unroll
            for (int i = 0; i < 4; ++i) zd[i] = (double)z_s[k][4 * g + i];
            #pragma unroll
            for (int j = 0; j < 4; ++j) ed[j] = (double)e_s[k][4 * h + j];
            #pragma unroll
            for (int i = 0; i < 4; ++i)
                #pragma unroll
                for (int j = 0; j < 4; ++j)
                    acc[i][j] = fma(zd[i], ed[j], acc[i][j]);
        }

        const int n0 = nt * NT;
        #pragma unroll
        for (int j = 0; j < 4; ++j) {
            const int n = n0 + 4 * h + j;           // ascending n per thread
            #pragma unroll
            for (int i = 0; i < 4; ++i) {
                const float dotf = (float)acc[i][j];             // round dot to fp32
                const float d = z2_s[4 * g + i] - 2.0f * dotf;   // fp32 grid (e^2 < ulp/2: no-op)
                if (d < bestd[i]) { bestd[i] = d; bestn[i] = n; }  // strict <: first-index ties
            }
        }
    }

    // ---- combine across the 16 col-groups, lexicographic (d, n)
    #pragma unroll
    for (int i = 0; i < 4; ++i) { red_d[4 * g + i][h] = bestd[i]; red_n[4 * g + i][h] = bestn[i]; }
    __syncthreads();

    if (tid < MT) {
        float bd = red_d[tid][0];
        int   bn = red_n[tid][0];
        for (int t = 1; t < 16; ++t) {
            const float d = red_d[tid][t];
            const int   n = red_n[tid][t];
            if (d < bd || (d == bd && n < bn)) { bd = d; bn = n; }
        }
        idx_s[tid] = bn;
        out[IDX_OFF + m0 + tid] = (float)bn;   // indices as float values
    }
    __syncthreads();

    // ---- gather emb[best] and write quantized + st (coalesced along hw)
    const int r  = tid & 63;
    const int c0 = tid >> 6;
    const int myn = idx_s[r];
    const float* erow = emb + (size_t)myn * KDIM;
    const size_t obase = (size_t)nimg * 262144 + hw0 + r;
    for (int c = c0; c < KDIM; c += 4) {
        const float qv = erow[c];
        out[obase + (size_t)c * 1024] = qv;
        out[ST_OFF + obase + (size_t)c * 1024] = qv;
    }
}

extern "C" void kernel_launch(void* const* d_in, const int* in_sizes, int n_in,
                              void* d_out, int out_size, void* d_ws, size_t ws_size,
                              hipStream_t stream) {
    const float* zp   = (const float*)d_in[0];
    const float* embp = (const float*)d_in[1];
    float* outp = (float*)d_out;
    vq_argmin_kernel<<<MTOTAL / MT, 256, 0, stream>>>(zp, embp, outp);
}